// Round 1
// baseline (713.458 us; speedup 1.0000x reference)
//
#include <hip/hip_runtime.h>
#include <hip/hip_bf16.h>

typedef __hip_bfloat16 bf16;

#define NB   32
#define NTT  512
#define NJ   17
#define ND   128
#define NP   6
#define NH   4
#define NDH  32
#define NBT  (NB*NTT)        // 16384 frames
#define NG   8               // frames per block
#define NTOK (NG*NP)         // 48 tokens per block
#define NTHR 256
#define WTSTR 132            // padded WT row stride (bf16 elems): 264 B, 8B-aligned, conflict-light

__constant__ int c_pidx[NP][5] = {{0,1,2,3,4},{5,6,11,12,0},{5,7,9,0,0},
                                  {6,8,10,0,0},{11,13,15,0,0},{12,14,16,0,0}};
__constant__ int c_plen[NP] = {5,4,3,3,3,3};

__device__ __forceinline__ float bf2f(unsigned short u) {
    return __uint_as_float(((unsigned)u) << 16);
}

// Stage a 128x128 fp32 weight matrix (row-major [dout][k]) into LDS transposed
// as bf16 WT[k][dout] with padded row stride. Global reads coalesced; LDS writes
// land on consecutive banks (stride 264B -> bank step 2, 2-way = free-ish).
__device__ __forceinline__ void stage_WT(const float* __restrict__ Wsrc,
                                         bf16* __restrict__ wt, int tid) {
    #pragma unroll 8
    for (int i = 0; i < (ND*ND)/NTHR; ++i) {
        int e    = i*NTHR + tid;
        int dout = e >> 7;
        int k    = e & (ND-1);
        wt[k*WTSTR + dout] = __float2bfloat16(Wsrc[e]);
    }
}

// out[token][dout] = bias[dout] + sum_k in[token][k] * WT[k][dout]   (48x128 @ 128x128)
// Thread map: dq = (tid&31)*4 douts, tg = tid>>5 owns tokens [tg*6, tg*6+6).
// MODE 0: fp32 store to outf (row stride 128)
// MODE 1: bf16 store to outb (row stride 384)
// MODE 2: fp32 store to outf with residual added
template<int MODE>
__device__ __forceinline__ void gemm48(const float* __restrict__ in,
                                       const bf16* __restrict__ wt,
                                       const float* __restrict__ bias,
                                       float* __restrict__ outf,
                                       bf16* __restrict__ outb,
                                       const float* __restrict__ resid,
                                       int tid)
{
    const int dq = (tid & 31) << 2;
    const int t0 = (tid >> 5) * 6;
    float acc[6][4];
    #pragma unroll
    for (int i = 0; i < 6; ++i) {
        acc[i][0]=0.f; acc[i][1]=0.f; acc[i][2]=0.f; acc[i][3]=0.f;
    }
    #pragma unroll 4
    for (int k4 = 0; k4 < ND/4; ++k4) {
        float w[4][4];
        #pragma unroll
        for (int kk = 0; kk < 4; ++kk) {
            ushort4 u = *reinterpret_cast<const ushort4*>(wt + (k4*4+kk)*WTSTR + dq);
            w[kk][0]=bf2f(u.x); w[kk][1]=bf2f(u.y); w[kk][2]=bf2f(u.z); w[kk][3]=bf2f(u.w);
        }
        #pragma unroll
        for (int i = 0; i < 6; ++i) {
            const float4 v = *reinterpret_cast<const float4*>(in + (t0+i)*ND + k4*4);
            #pragma unroll
            for (int j = 0; j < 4; ++j) {
                acc[i][j] += v.x*w[0][j];
                acc[i][j] += v.y*w[1][j];
                acc[i][j] += v.z*w[2][j];
                acc[i][j] += v.w*w[3][j];
            }
        }
    }
    float bv0 = bias[dq], bv1 = bias[dq+1], bv2 = bias[dq+2], bv3 = bias[dq+3];
    #pragma unroll
    for (int i = 0; i < 6; ++i) {
        float r0 = acc[i][0]+bv0, r1 = acc[i][1]+bv1, r2 = acc[i][2]+bv2, r3 = acc[i][3]+bv3;
        if (MODE == 2) {
            const float* rp = resid + (t0+i)*ND + dq;
            r0 += rp[0]; r1 += rp[1]; r2 += rp[2]; r3 += rp[3];
        }
        if (MODE == 1) {
            bf16* dst = outb + (t0+i)*(3*ND) + dq;
            dst[0] = __float2bfloat16(r0);
            dst[1] = __float2bfloat16(r1);
            dst[2] = __float2bfloat16(r2);
            dst[3] = __float2bfloat16(r3);
        } else {
            float4 r; r.x=r0; r.y=r1; r.z=r2; r.w=r3;
            *reinterpret_cast<float4*>(outf + (t0+i)*ND + dq) = r;
        }
    }
}

extern "C" __global__ __launch_bounds__(NTHR)
void bpa_fused(const float* __restrict__ h_joint,
               const float* __restrict__ mask_joint,
               const float* __restrict__ W_proj, const float* __restrict__ b_proj,
               const float* __restrict__ W_in,  const float* __restrict__ b_in,
               const float* __restrict__ W_out, const float* __restrict__ b_out,
               const float* __restrict__ ln_g,  const float* __restrict__ ln_b,
               float* __restrict__ out)
{
    __shared__ float s_pool[NTOK*ND];       // pooled tokens; reused as o after attention
    __shared__ float s_tokp[NTOK*ND];       // proj output (residual source)
    __shared__ bf16  s_WT[ND*WTSTR];        // staged transposed weight chunk
    __shared__ bf16  s_qkv[NTOK*3*ND];      // q|k|v bf16; later aliased as fp32 y[48][128]
    __shared__ float s_probs[NG*NH*NP*NP];  // softmax probs
    __shared__ float s_mu[NTOK];
    __shared__ float s_inv[NTOK];

    float* s_y = reinterpret_cast<float*>(s_qkv);   // 24.5 KB into 36.8 KB region

    const int tid = threadIdx.x;
    const long frame0 = (long)blockIdx.x * NG;

    // ---- Stage 1: mask-aware mean pooling into s_pool, + stage W_proj^T ----
    #pragma unroll 4
    for (int i = 0; i < (NTOK*ND)/NTHR; ++i) {   // 24 iters
        int idx = i*NTHR + tid;
        int token = idx >> 7;
        int d = idx & (ND-1);
        int f = token / NP, p = token - f*NP;
        const float* hrow = h_joint + (frame0 + f)*(long)(NJ*ND);
        const float* mrow = mask_joint + (frame0 + f)*(long)NJ;
        int len = c_plen[p];
        float s = 0.f, cnt = 0.f;
        #pragma unroll
        for (int l = 0; l < 5; ++l) {
            int j = c_pidx[p][l];
            float mv = mrow[j];
            bool use = (l < len) && (mv > 0.05f);
            if (use) { s += hrow[j*ND + d]; cnt += 1.f; }
        }
        s_pool[token*ND + d] = s / fmaxf(cnt, 1e-6f);
    }
    stage_WT(W_proj, s_WT, tid);
    __syncthreads();

    // ---- Stage 2: proj_in -> s_tokp ----
    gemm48<0>(s_pool, s_WT, b_proj, s_tokp, nullptr, nullptr, tid);
    __syncthreads();

    // ---- Stage 3: qkv = tokp @ W_in^T + b_in (3 chunks of 128) -> s_qkv bf16 ----
    for (int c = 0; c < 3; ++c) {
        stage_WT(W_in + c*ND*ND, s_WT, tid);
        __syncthreads();
        gemm48<1>(s_tokp, s_WT, b_in + c*ND, nullptr, s_qkv + c*ND, nullptr, tid);
        __syncthreads();
    }

    // ---- Stage 4: attention scores + softmax -> s_probs ----
    if (tid < NG*NH*NP) {   // 192 threads: (f, h, qi)
        int f   = tid / (NH*NP);
        int rem = tid - f*(NH*NP);
        int h   = rem / NP;
        int qi  = rem - h*NP;
        const bf16* qrow = s_qkv + (f*NP+qi)*(3*ND) + h*NDH;
        float sc[NP];
        float mx = -1e30f;
        #pragma unroll
        for (int pk = 0; pk < NP; ++pk) {
            const bf16* krow = s_qkv + (f*NP+pk)*(3*ND) + ND + h*NDH;
            float s = 0.f;
            #pragma unroll
            for (int c = 0; c < NDH; c += 4) {
                ushort4 uq = *reinterpret_cast<const ushort4*>(qrow + c);
                ushort4 uk = *reinterpret_cast<const ushort4*>(krow + c);
                s += bf2f(uq.x)*bf2f(uk.x) + bf2f(uq.y)*bf2f(uk.y)
                   + bf2f(uq.z)*bf2f(uk.z) + bf2f(uq.w)*bf2f(uk.w);
            }
            sc[pk] = s * 0.17677669529663688f;   // 1/sqrt(32)
            mx = fmaxf(mx, sc[pk]);
        }
        float den = 0.f, e[NP];
        #pragma unroll
        for (int pk = 0; pk < NP; ++pk) { e[pk] = expf(sc[pk]-mx); den += e[pk]; }
        float inv = 1.f/den;
        #pragma unroll
        for (int pk = 0; pk < NP; ++pk)
            s_probs[((f*NH+h)*NP+qi)*NP + pk] = e[pk]*inv;
    }
    __syncthreads();

    // ---- Stage 5: part_importance + o = w @ v (o into s_pool) ----
    if (tid < NG*NP) {  // 48 threads: (f, pk)
        int f = tid / NP, pk = tid - f*NP;
        float s = 0.f;
        #pragma unroll
        for (int h = 0; h < NH; ++h)
            #pragma unroll
            for (int q = 0; q < NP; ++q)
                s += s_probs[((f*NH+h)*NP+q)*NP + pk];
        out[(long)NBT*NP*ND + (frame0+f)*NP + pk] = s * (1.f/24.f);
    }
    #pragma unroll 4
    for (int i = 0; i < (NTOK*ND)/NTHR; ++i) {
        int idx = i*NTHR + tid;
        int token = idx >> 7;
        int d = idx & (ND-1);
        int f = token / NP, qi = token - f*NP;
        int h = d >> 5;
        const float* pr = s_probs + ((f*NH+h)*NP+qi)*NP;
        float s = 0.f;
        #pragma unroll
        for (int pk = 0; pk < NP; ++pk) {
            float v = bf2f(reinterpret_cast<const unsigned short*>(s_qkv)[(f*NP+pk)*(3*ND) + 2*ND + d]);
            s += pr[pk]*v;
        }
        s_pool[token*ND + d] = s;
    }
    __syncthreads();

    // ---- Stage 6: out-proj + residual -> s_y ----
    stage_WT(W_out, s_WT, tid);
    __syncthreads();
    gemm48<2>(s_pool, s_WT, b_out, s_y, nullptr, s_tokp, tid);
    __syncthreads();

    // ---- Stage 7: LayerNorm stats (4 lanes per token) ----
    if (tid < NTOK*4) {   // 192 threads
        int token = tid >> 2, sub = tid & 3;
        const float* row = s_y + token*ND + sub*NDH;
        float s = 0.f, s2 = 0.f;
        #pragma unroll
        for (int j = 0; j < NDH; j += 4) {
            float4 v = *reinterpret_cast<const float4*>(row + j);
            s  += v.x + v.y + v.z + v.w;
            s2 += v.x*v.x + v.y*v.y + v.z*v.z + v.w*v.w;
        }
        s  += __shfl_xor(s, 1);  s  += __shfl_xor(s, 2);
        s2 += __shfl_xor(s2, 1); s2 += __shfl_xor(s2, 2);
        float mean = s * (1.f/128.f);
        float var  = s2 * (1.f/128.f) - mean*mean;
        if (sub == 0) {
            s_mu[token]  = mean;
            s_inv[token] = rsqrtf(var + 1e-5f);
        }
    }
    __syncthreads();

    // ---- Stage 8: normalize + coalesced store ----
    #pragma unroll
    for (int i = 0; i < (NTOK*ND)/(NTHR*4); ++i) {   // 6 iters, float4 per thread
        int idx4 = i*NTHR + tid;
        int token = idx4 >> 5;              // 32 float4 per token row
        int dj = (idx4 & 31) << 2;
        float mean = s_mu[token], inv = s_inv[token];
        float4 v = *reinterpret_cast<const float4*>(s_y + token*ND + dj);
        float4 g = *reinterpret_cast<const float4*>(ln_g + dj);
        float4 b = *reinterpret_cast<const float4*>(ln_b + dj);
        float4 r;
        r.x = (v.x-mean)*inv*g.x + b.x;
        r.y = (v.y-mean)*inv*g.y + b.y;
        r.z = (v.z-mean)*inv*g.z + b.z;
        r.w = (v.w-mean)*inv*g.w + b.w;
        *reinterpret_cast<float4*>(out + (frame0*NP + token)*(long)ND + dj) = r;
    }
}

extern "C" void kernel_launch(void* const* d_in, const int* in_sizes, int n_in,
                              void* d_out, int out_size, void* d_ws, size_t ws_size,
                              hipStream_t stream) {
    const float* h_joint = (const float*)d_in[0];
    const float* mask    = (const float*)d_in[1];
    const float* W_proj  = (const float*)d_in[2];
    const float* b_proj  = (const float*)d_in[3];
    const float* W_in    = (const float*)d_in[4];
    const float* b_in    = (const float*)d_in[5];
    const float* W_out   = (const float*)d_in[6];
    const float* b_out   = (const float*)d_in[7];
    const float* ln_g    = (const float*)d_in[8];
    const float* ln_b    = (const float*)d_in[9];
    float* out = (float*)d_out;

    dim3 grid(NBT/NG), block(NTHR);
    hipLaunchKernelGGL(bpa_fused, grid, block, 0, stream,
                       h_joint, mask, W_proj, b_proj, W_in, b_in,
                       W_out, b_out, ln_g, ln_b, out);
}

// Round 2
// 309.591 us; speedup vs baseline: 2.3045x; 2.3045x over previous
//
#include <hip/hip_runtime.h>
#include <hip/hip_bf16.h>

typedef __hip_bfloat16 bf16;
typedef __attribute__((ext_vector_type(8))) short short8v;   // bf16x8 MFMA fragment
typedef __attribute__((ext_vector_type(4))) float f32x4;     // MFMA accumulator

#define NB   32
#define NTT  512
#define NJ   17
#define ND   128
#define NP   6
#define NH   4
#define NDH  32
#define NBT  (NB*NTT)        // 16384 frames
#define NG   8               // frames per block
#define NTOK (NG*NP)         // 48 tokens per block
#define NTHR 256             // 4 waves
#define TSTR 136             // bf16 token row stride: 272B = 16B-aligned, bank-step 4
#define QSTR 408             // qkv row stride (3*136): 816B, 16B-aligned
#define YSTR 132             // y fp32 row stride: 528B, 16B-aligned

__constant__ int c_pidx[NP][5] = {{0,1,2,3,4},{5,6,11,12,0},{5,7,9,0,0},
                                  {6,8,10,0,0},{11,13,15,0,0},{12,14,16,0,0}};
__constant__ int c_plen[NP] = {5,4,3,3,3,3};

__device__ __forceinline__ float bf2f(unsigned short u) {
    return __uint_as_float(((unsigned)u) << 16);
}
__device__ __forceinline__ short f2bs(float x) {
    bf16 h = __float2bfloat16(x);
    return *reinterpret_cast<short*>(&h);
}
__device__ __forceinline__ f32x4 MFMA(short8v a, short8v b, f32x4 c) {
    return __builtin_amdgcn_mfma_f32_16x16x32_bf16(a, b, c, 0, 0, 0);
}

// B-fragment: lane reads 8 consecutive k (fp32) of weight row n = nt*16 + (lane&15),
// converts to bf16. W row-major [dout][k] IS B^T, exactly the layout MFMA's B wants.
__device__ __forceinline__ short8v ldB(const float* __restrict__ W, int nt, int ks, int lane) {
    const float* p = W + (nt*16 + (lane & 15)) * ND + ks*32 + ((lane >> 4) << 3);
    float4 u = *reinterpret_cast<const float4*>(p);
    float4 v = *reinterpret_cast<const float4*>(p + 4);
    short8v r;
    r[0]=f2bs(u.x); r[1]=f2bs(u.y); r[2]=f2bs(u.z); r[3]=f2bs(u.w);
    r[4]=f2bs(v.x); r[5]=f2bs(v.y); r[6]=f2bs(v.z); r[7]=f2bs(v.w);
    return r;
}
// A-fragment from bf16 LDS tile (row stride TSTR): 16B vector read, 16B-aligned.
__device__ __forceinline__ short8v ldsA(const bf16* __restrict__ s, int mt, int ks, int lane) {
    return *reinterpret_cast<const short8v*>(s + (mt*16 + (lane & 15))*TSTR + ks*32 + ((lane >> 4) << 3));
}

extern "C" __global__ __launch_bounds__(NTHR, 2)
void bpa_fused(const float* __restrict__ h_joint,
               const float* __restrict__ mask_joint,
               const float* __restrict__ W_proj, const float* __restrict__ b_proj,
               const float* __restrict__ W_in,  const float* __restrict__ b_in,
               const float* __restrict__ W_out, const float* __restrict__ b_out,
               const float* __restrict__ ln_g,  const float* __restrict__ ln_b,
               float* __restrict__ out)
{
    __shared__ __align__(16) bf16 s_pool[NTOK*TSTR];   // pooled tokens; later o (PV out)
    __shared__ __align__(16) bf16 s_tokp[NTOK*TSTR];   // proj out: qkv-A + residual
    __shared__ __align__(16) bf16 s_qkv[NTOK*QSTR];    // q|k|v ; later aliased as fp32 y
    __shared__ float s_probs[NG*NH*NP*NP];
    __shared__ float s_mu[NTOK];
    __shared__ float s_inv[NTOK];
    float* s_y = reinterpret_cast<float*>(s_qkv);      // [48][YSTR] fp32, fits in qkv region

    const int tid  = threadIdx.x;
    const int lane = tid & 63;
    const int w    = tid >> 6;
    const long frame0 = (long)blockIdx.x * NG;

    // ---- Prefetch proj B-fragments from global (L2-hot), independent of LDS ----
    short8v bp[2][4];
    #pragma unroll
    for (int n2 = 0; n2 < 2; ++n2)
        #pragma unroll
        for (int ks = 0; ks < 4; ++ks)
            bp[n2][ks] = ldB(W_proj, w*2 + n2, ks, lane);

    // ---- Stage 1: mask-aware mean pooling -> s_pool (bf16) ----
    #pragma unroll 4
    for (int i = 0; i < (NTOK*ND)/NTHR; ++i) {   // 24 iters
        int idx = i*NTHR + tid;
        int token = idx >> 7;
        int d = idx & (ND-1);
        int f = token / NP, p = token - f*NP;
        const float* hrow = h_joint + (frame0 + f)*(long)(NJ*ND);
        const float* mrow = mask_joint + (frame0 + f)*(long)NJ;
        int len = c_plen[p];
        float s = 0.f, cnt = 0.f;
        #pragma unroll
        for (int l = 0; l < 5; ++l) {
            int j = c_pidx[p][l];
            float mv = mrow[j];
            bool use = (l < len) && (mv > 0.05f);
            if (use) { s += hrow[j*ND + d]; cnt += 1.f; }
        }
        s_pool[token*TSTR + d] = __float2bfloat16(s / fmaxf(cnt, 1e-6f));
    }
    __syncthreads();

    // ---- Stage 2: proj = pool @ Wp^T + b (MFMA, wave w owns N-tiles 2w,2w+1) ----
    {
        f32x4 acc[3][2];
        #pragma unroll
        for (int m = 0; m < 3; ++m) { acc[m][0] = (f32x4)(0.f); acc[m][1] = (f32x4)(0.f); }
        #pragma unroll
        for (int ks = 0; ks < 4; ++ks) {
            #pragma unroll
            for (int mt = 0; mt < 3; ++mt) {
                short8v a = ldsA(s_pool, mt, ks, lane);
                acc[mt][0] = MFMA(a, bp[0][ks], acc[mt][0]);
                acc[mt][1] = MFMA(a, bp[1][ks], acc[mt][1]);
            }
        }
        #pragma unroll
        for (int n2 = 0; n2 < 2; ++n2) {
            int col = (w*2 + n2)*16 + (lane & 15);
            float bv = b_proj[col];
            #pragma unroll
            for (int mt = 0; mt < 3; ++mt)
                #pragma unroll
                for (int j = 0; j < 4; ++j) {
                    int row = mt*16 + ((lane >> 4) << 2) + j;
                    s_tokp[row*TSTR + col] = __float2bfloat16(acc[mt][n2][j] + bv);
                }
        }
    }
    __syncthreads();

    // ---- Stage 3: qkv = tokp @ Win^T + b (wave w owns N-tiles 6w..6w+5 of 24) ----
    {
        short8v a[3][4];
        #pragma unroll
        for (int mt = 0; mt < 3; ++mt)
            #pragma unroll
            for (int ks = 0; ks < 4; ++ks)
                a[mt][ks] = ldsA(s_tokp, mt, ks, lane);
        for (int n6 = 0; n6 < 6; ++n6) {
            int nt = w*6 + n6;                       // global N-tile 0..23 (cols 0..383)
            short8v b[4];
            #pragma unroll
            for (int ks = 0; ks < 4; ++ks) b[ks] = ldB(W_in, nt, ks, lane);
            f32x4 acc[3];
            acc[0] = (f32x4)(0.f); acc[1] = (f32x4)(0.f); acc[2] = (f32x4)(0.f);
            #pragma unroll
            for (int ks = 0; ks < 4; ++ks)
                #pragma unroll
                for (int mt = 0; mt < 3; ++mt)
                    acc[mt] = MFMA(a[mt][ks], b[ks], acc[mt]);
            int col = nt*16 + (lane & 15);           // 0..383
            float bv = b_in[col];
            #pragma unroll
            for (int mt = 0; mt < 3; ++mt)
                #pragma unroll
                for (int j = 0; j < 4; ++j) {
                    int row = mt*16 + ((lane >> 4) << 2) + j;
                    s_qkv[row*QSTR + col] = __float2bfloat16(acc[mt][j] + bv);
                }
        }
    }
    __syncthreads();

    // ---- Stage 4: attention scores + softmax -> s_probs ----
    if (tid < NG*NH*NP) {   // 192 threads: (f, h, qi)
        int f   = tid / (NH*NP);
        int rem = tid - f*(NH*NP);
        int h   = rem / NP;
        int qi  = rem - h*NP;
        const bf16* qrow = s_qkv + (f*NP+qi)*QSTR + h*NDH;
        float sc[NP];
        float mx = -1e30f;
        #pragma unroll
        for (int pk = 0; pk < NP; ++pk) {
            const bf16* krow = s_qkv + (f*NP+pk)*QSTR + ND + h*NDH;
            float s = 0.f;
            #pragma unroll
            for (int c = 0; c < NDH; c += 4) {
                ushort4 uq = *reinterpret_cast<const ushort4*>(qrow + c);
                ushort4 uk = *reinterpret_cast<const ushort4*>(krow + c);
                s += bf2f(uq.x)*bf2f(uk.x) + bf2f(uq.y)*bf2f(uk.y)
                   + bf2f(uq.z)*bf2f(uk.z) + bf2f(uq.w)*bf2f(uk.w);
            }
            sc[pk] = s * 0.17677669529663688f;   // 1/sqrt(32)
            mx = fmaxf(mx, sc[pk]);
        }
        float den = 0.f, e[NP];
        #pragma unroll
        for (int pk = 0; pk < NP; ++pk) { e[pk] = expf(sc[pk]-mx); den += e[pk]; }
        float inv = 1.f/den;
        #pragma unroll
        for (int pk = 0; pk < NP; ++pk)
            s_probs[((f*NH+h)*NP+qi)*NP + pk] = e[pk]*inv;
    }
    __syncthreads();

    // ---- Stage 5: part_importance + o = w @ v (o -> s_pool, bf16) ----
    if (tid < NG*NP) {  // 48 threads: (f, pk)
        int f = tid / NP, pk = tid - f*NP;
        float s = 0.f;
        #pragma unroll
        for (int h = 0; h < NH; ++h)
            #pragma unroll
            for (int q = 0; q < NP; ++q)
                s += s_probs[((f*NH+h)*NP+q)*NP + pk];
        out[(long)NBT*NP*ND + (frame0+f)*NP + pk] = s * (1.f/24.f);
    }
    #pragma unroll 4
    for (int i = 0; i < (NTOK*ND)/NTHR; ++i) {
        int idx = i*NTHR + tid;
        int token = idx >> 7;
        int d = idx & (ND-1);
        int f = token / NP, qi = token - f*NP;
        int h = d >> 5;
        const float* pr = s_probs + ((f*NH+h)*NP+qi)*NP;
        float s = 0.f;
        #pragma unroll
        for (int pk = 0; pk < NP; ++pk) {
            float v = bf2f(reinterpret_cast<const unsigned short*>(s_qkv)[(f*NP+pk)*QSTR + 2*ND + d]);
            s += pr[pk]*v;
        }
        s_pool[token*TSTR + d] = __float2bfloat16(s);
    }
    __syncthreads();

    // ---- Stage 6: y = o @ Wout^T + b + resid -> fp32 y (aliases qkv region) ----
    {
        short8v bo[2][4];
        #pragma unroll
        for (int n2 = 0; n2 < 2; ++n2)
            #pragma unroll
            for (int ks = 0; ks < 4; ++ks)
                bo[n2][ks] = ldB(W_out, w*2 + n2, ks, lane);
        f32x4 acc[3][2];
        #pragma unroll
        for (int m = 0; m < 3; ++m) { acc[m][0] = (f32x4)(0.f); acc[m][1] = (f32x4)(0.f); }
        #pragma unroll
        for (int ks = 0; ks < 4; ++ks) {
            #pragma unroll
            for (int mt = 0; mt < 3; ++mt) {
                short8v a = ldsA(s_pool, mt, ks, lane);
                acc[mt][0] = MFMA(a, bo[0][ks], acc[mt][0]);
                acc[mt][1] = MFMA(a, bo[1][ks], acc[mt][1]);
            }
        }
        __syncthreads();   // ensure all qkv reads (stage 4/5 done) before y overwrite
        #pragma unroll
        for (int n2 = 0; n2 < 2; ++n2) {
            int col = (w*2 + n2)*16 + (lane & 15);
            float bv = b_out[col];
            #pragma unroll
            for (int mt = 0; mt < 3; ++mt)
                #pragma unroll
                for (int j = 0; j < 4; ++j) {
                    int row = mt*16 + ((lane >> 4) << 2) + j;
                    float resid = bf2f(*reinterpret_cast<const unsigned short*>(&s_tokp[row*TSTR + col]));
                    s_y[row*YSTR + col] = acc[mt][n2][j] + bv + resid;
                }
        }
    }
    __syncthreads();

    // ---- Stage 7: LayerNorm stats (4 lanes per token) ----
    if (tid < NTOK*4) {   // 192 threads
        int token = tid >> 2, sub = tid & 3;
        const float* row = s_y + token*YSTR + sub*NDH;
        float s = 0.f, s2 = 0.f;
        #pragma unroll
        for (int j = 0; j < NDH; j += 4) {
            float4 v = *reinterpret_cast<const float4*>(row + j);
            s  += v.x + v.y + v.z + v.w;
            s2 += v.x*v.x + v.y*v.y + v.z*v.z + v.w*v.w;
        }
        s  += __shfl_xor(s, 1);  s  += __shfl_xor(s, 2);
        s2 += __shfl_xor(s2, 1); s2 += __shfl_xor(s2, 2);
        float mean = s * (1.f/128.f);
        float var  = s2 * (1.f/128.f) - mean*mean;
        if (sub == 0) {
            s_mu[token]  = mean;
            s_inv[token] = rsqrtf(var + 1e-5f);
        }
    }
    __syncthreads();

    // ---- Stage 8: normalize + coalesced store ----
    #pragma unroll
    for (int i = 0; i < (NTOK*ND)/(NTHR*4); ++i) {   // 6 iters, float4 per thread
        int idx4 = i*NTHR + tid;
        int token = idx4 >> 5;
        int dj = (idx4 & 31) << 2;
        float mean = s_mu[token], inv = s_inv[token];
        float4 v = *reinterpret_cast<const float4*>(s_y + token*YSTR + dj);
        float4 g = *reinterpret_cast<const float4*>(ln_g + dj);
        float4 b = *reinterpret_cast<const float4*>(ln_b + dj);
        float4 r;
        r.x = (v.x-mean)*inv*g.x + b.x;
        r.y = (v.y-mean)*inv*g.y + b.y;
        r.z = (v.z-mean)*inv*g.z + b.z;
        r.w = (v.w-mean)*inv*g.w + b.w;
        *reinterpret_cast<float4*>(out + (frame0*NP + token)*(long)ND + dj) = r;
    }
}

extern "C" void kernel_launch(void* const* d_in, const int* in_sizes, int n_in,
                              void* d_out, int out_size, void* d_ws, size_t ws_size,
                              hipStream_t stream) {
    const float* h_joint = (const float*)d_in[0];
    const float* mask    = (const float*)d_in[1];
    const float* W_proj  = (const float*)d_in[2];
    const float* b_proj  = (const float*)d_in[3];
    const float* W_in    = (const float*)d_in[4];
    const float* b_in    = (const float*)d_in[5];
    const float* W_out   = (const float*)d_in[6];
    const float* b_out   = (const float*)d_in[7];
    const float* ln_g    = (const float*)d_in[8];
    const float* ln_b    = (const float*)d_in[9];
    float* out = (float*)d_out;

    dim3 grid(NBT/NG), block(NTHR);
    hipLaunchKernelGGL(bpa_fused, grid, block, 0, stream,
                       h_joint, mask, W_proj, b_proj, W_in, b_in,
                       W_out, b_out, ln_g, ln_b, out);
}

// Round 3
// 198.889 us; speedup vs baseline: 3.5872x; 1.5566x over previous
//
#include <hip/hip_runtime.h>
#include <hip/hip_bf16.h>

typedef __hip_bfloat16 bf16;
typedef __attribute__((ext_vector_type(8))) short short8v;   // bf16x8 MFMA fragment
typedef __attribute__((ext_vector_type(4))) float f32x4;     // MFMA accumulator

#define NB   32
#define NTT  512
#define NJ   17
#define ND   128
#define NP   6
#define NH   4
#define NDH  32
#define NBT  (NB*NTT)        // 16384 frames
#define NG   8               // frames per block
#define NTOK (NG*NP)         // 48 tokens per block
#define NTHR 512             // 8 waves
#define NWAVE 8
#define TSTR 136             // bf16 row stride: 272B, 16B-aligned
#define QKSTR 272            // q|k row stride (bf16): 544B, 16B-aligned
#define YSTR 132             // y fp32 row stride: 528B, 16B-aligned

// ws layout (bf16): [0,16384) W_proj | [16384,65536) W_in | [65536,81920) W_out
#define WS_WP 0
#define WS_WI 16384
#define WS_WO 65536

__constant__ int c_pidx[NP][5] = {{0,1,2,3,4},{5,6,11,12,0},{5,7,9,0,0},
                                  {6,8,10,0,0},{11,13,15,0,0},{12,14,16,0,0}};
__constant__ int c_plen[NP] = {5,4,3,3,3,3};

__device__ __forceinline__ float bf2f(unsigned short u) {
    return __uint_as_float(((unsigned)u) << 16);
}
__device__ __forceinline__ f32x4 MFMA(short8v a, short8v b, f32x4 c) {
    return __builtin_amdgcn_mfma_f32_16x16x32_bf16(a, b, c, 0, 0, 0);
}
// B-fragment from bf16 weight (row-major [dout][k] == B^T): one 16B load.
__device__ __forceinline__ short8v ldB(const bf16* __restrict__ W, int nt, int ks, int lane) {
    return *reinterpret_cast<const short8v*>(W + (nt*16 + (lane & 15))*ND + ks*32 + ((lane >> 4) << 3));
}
// A-fragment from bf16 LDS tile with row stride `str`.
__device__ __forceinline__ short8v ldsA(const bf16* __restrict__ s, int str, int mt, int ks, int lane) {
    return *reinterpret_cast<const short8v*>(s + (mt*16 + (lane & 15))*str + ks*32 + ((lane >> 4) << 3));
}

// ---- K0: one-shot fp32 -> bf16 weight conversion into d_ws ----
extern "C" __global__ __launch_bounds__(256)
void wconv(const float* __restrict__ Wp, const float* __restrict__ Wi,
           const float* __restrict__ Wo, bf16* __restrict__ ws) {
    int i = blockIdx.x*256 + threadIdx.x;     // 81920 total
    float v;
    if (i < 16384)      v = Wp[i];
    else if (i < 65536) v = Wi[i - 16384];
    else                v = Wo[i - 65536];
    ws[i] = __float2bfloat16(v);
}

extern "C" __global__ __launch_bounds__(NTHR, 4)
void bpa_fused(const float* __restrict__ h_joint,
               const float* __restrict__ mask_joint,
               const bf16* __restrict__ wgt,
               const float* __restrict__ b_proj, const float* __restrict__ b_in,
               const float* __restrict__ b_out,
               const float* __restrict__ ln_g,  const float* __restrict__ ln_b,
               float* __restrict__ out)
{
    __shared__ __align__(16) bf16 s_pool[NTOK*TSTR];   // pooled tokens; then v
    __shared__ __align__(16) bf16 s_tokp[NTOK*TSTR];   // proj out (A + residual)
    __shared__ __align__(16) bf16 s_qk[NTOK*QKSTR];    // q|k ; o over q; then y fp32
    __shared__ float s_probs[NG*NH*NP*NP];
    __shared__ float s_mu[NTOK];
    __shared__ float s_inv[NTOK];
    float* s_y = reinterpret_cast<float*>(s_qk);       // [48][YSTR] fp32 (25.3KB <= 26.1KB)

    const int tid  = threadIdx.x;
    const int lane = tid & 63;
    const int w    = tid >> 6;                          // wave 0..7
    const long frame0 = (long)blockIdx.x * NG;

    // Prefetch W_proj B-fragments (tile w) — overlaps with pooling loads.
    short8v bp[4];
    #pragma unroll
    for (int ks = 0; ks < 4; ++ks) bp[ks] = ldB(wgt + WS_WP, w, ks, lane);

    // ---- Stage 1: mask-aware mean pooling -> s_pool (bf16) ----
    #pragma unroll 4
    for (int i = 0; i < (NTOK*ND)/NTHR; ++i) {   // 12 iters
        int idx = i*NTHR + tid;
        int token = idx >> 7;
        int d = idx & (ND-1);
        int f = token / NP, p = token - f*NP;
        const float* hrow = h_joint + (frame0 + f)*(long)(NJ*ND);
        const float* mrow = mask_joint + (frame0 + f)*(long)NJ;
        int len = c_plen[p];
        float s = 0.f, cnt = 0.f;
        #pragma unroll
        for (int l = 0; l < 5; ++l) {
            int j = c_pidx[p][l];
            float mv = mrow[j];
            bool use = (l < len) && (mv > 0.05f);
            if (use) { s += hrow[j*ND + d]; cnt += 1.f; }
        }
        s_pool[token*TSTR + d] = __float2bfloat16(s / fmaxf(cnt, 1e-6f));
    }
    __syncthreads();

    // ---- Stage 2: proj = pool @ Wp^T + b  (wave w owns N-tile w) ----
    {
        f32x4 acc[3];
        acc[0] = (f32x4)(0.f); acc[1] = (f32x4)(0.f); acc[2] = (f32x4)(0.f);
        #pragma unroll
        for (int ks = 0; ks < 4; ++ks)
            #pragma unroll
            for (int mt = 0; mt < 3; ++mt)
                acc[mt] = MFMA(ldsA(s_pool, TSTR, mt, ks, lane), bp[ks], acc[mt]);
        int col = w*16 + (lane & 15);
        float bv = b_proj[col];
        #pragma unroll
        for (int mt = 0; mt < 3; ++mt)
            #pragma unroll
            for (int j = 0; j < 4; ++j) {
                int row = mt*16 + ((lane >> 4) << 2) + j;
                s_tokp[row*TSTR + col] = __float2bfloat16(acc[mt][j] + bv);
            }
    }
    __syncthreads();

    // ---- Stage 3: qkv = tokp @ Win^T + b (wave w owns tiles w, 8+w, 16+w) ----
    #pragma unroll
    for (int t = 0; t < 3; ++t) {
        int nt = t*8 + w;                       // t=0:q, t=1:k, t=2:v
        short8v b[4];
        #pragma unroll
        for (int ks = 0; ks < 4; ++ks) b[ks] = ldB(wgt + WS_WI, nt, ks, lane);
        f32x4 acc[3];
        acc[0] = (f32x4)(0.f); acc[1] = (f32x4)(0.f); acc[2] = (f32x4)(0.f);
        #pragma unroll
        for (int ks = 0; ks < 4; ++ks)
            #pragma unroll
            for (int mt = 0; mt < 3; ++mt)
                acc[mt] = MFMA(ldsA(s_tokp, TSTR, mt, ks, lane), b[ks], acc[mt]);
        int col = nt*16 + (lane & 15);          // 0..383
        float bv = b_in[col];
        #pragma unroll
        for (int mt = 0; mt < 3; ++mt)
            #pragma unroll
            for (int j = 0; j < 4; ++j) {
                int row = mt*16 + ((lane >> 4) << 2) + j;
                float v = acc[mt][j] + bv;
                if (t < 2) s_qk[row*QKSTR + col] = __float2bfloat16(v);
                else       s_pool[row*TSTR + (col - 256)] = __float2bfloat16(v);
            }
    }
    __syncthreads();

    // ---- Stage 4: attention scores + softmax -> s_probs ----
    if (tid < NG*NH*NP) {   // 192 threads: (f, h, qi)
        int f   = tid / (NH*NP);
        int rem = tid - f*(NH*NP);
        int h   = rem / NP;
        int qi  = rem - h*NP;
        const bf16* qrow = s_qk + (f*NP+qi)*QKSTR + h*NDH;
        float sc[NP];
        float mx = -1e30f;
        #pragma unroll
        for (int pk = 0; pk < NP; ++pk) {
            const bf16* krow = s_qk + (f*NP+pk)*QKSTR + ND + h*NDH;
            float s = 0.f;
            #pragma unroll
            for (int c = 0; c < NDH; c += 4) {
                ushort4 uq = *reinterpret_cast<const ushort4*>(qrow + c);
                ushort4 uk = *reinterpret_cast<const ushort4*>(krow + c);
                s += bf2f(uq.x)*bf2f(uk.x) + bf2f(uq.y)*bf2f(uk.y)
                   + bf2f(uq.z)*bf2f(uk.z) + bf2f(uq.w)*bf2f(uk.w);
            }
            sc[pk] = s * 0.17677669529663688f;   // 1/sqrt(32)
            mx = fmaxf(mx, sc[pk]);
        }
        float den = 0.f, e[NP];
        #pragma unroll
        for (int pk = 0; pk < NP; ++pk) { e[pk] = expf(sc[pk]-mx); den += e[pk]; }
        float inv = 1.f/den;
        #pragma unroll
        for (int pk = 0; pk < NP; ++pk)
            s_probs[((f*NH+h)*NP+qi)*NP + pk] = e[pk]*inv;
    }
    __syncthreads();

    // ---- Stage 5: part_importance + o = w @ v (o over q region of s_qk) ----
    if (tid < NG*NP) {  // 48 threads: (f, pk)
        int f = tid / NP, pk = tid - f*NP;
        float s = 0.f;
        #pragma unroll
        for (int h = 0; h < NH; ++h)
            #pragma unroll
            for (int q = 0; q < NP; ++q)
                s += s_probs[((f*NH+h)*NP+q)*NP + pk];
        out[(long)NBT*NP*ND + (frame0+f)*NP + pk] = s * (1.f/24.f);
    }
    #pragma unroll 4
    for (int i = 0; i < (NTOK*ND)/NTHR; ++i) {   // 12 iters
        int idx = i*NTHR + tid;
        int token = idx >> 7;
        int d = idx & (ND-1);
        int f = token / NP, qi = token - f*NP;
        int h = d >> 5;
        const float* pr = s_probs + ((f*NH+h)*NP+qi)*NP;
        float s = 0.f;
        #pragma unroll
        for (int pk = 0; pk < NP; ++pk) {
            float v = bf2f(reinterpret_cast<const unsigned short*>(s_pool)[(f*NP+pk)*TSTR + d]);
            s += pr[pk]*v;
        }
        s_qk[token*QKSTR + d] = __float2bfloat16(s);   // o over dead q
    }
    __syncthreads();

    // ---- Stage 6: y = o @ Wout^T + b + resid -> fp32 y (aliases s_qk) ----
    {
        short8v bo[4];
        #pragma unroll
        for (int ks = 0; ks < 4; ++ks) bo[ks] = ldB(wgt + WS_WO, w, ks, lane);
        f32x4 acc[3];
        acc[0] = (f32x4)(0.f); acc[1] = (f32x4)(0.f); acc[2] = (f32x4)(0.f);
        #pragma unroll
        for (int ks = 0; ks < 4; ++ks)
            #pragma unroll
            for (int mt = 0; mt < 3; ++mt)
                acc[mt] = MFMA(ldsA(s_qk, QKSTR, mt, ks, lane), bo[ks], acc[mt]);
        __syncthreads();   // all o reads done before y overwrites the region
        int col = w*16 + (lane & 15);
        float bv = b_out[col];
        #pragma unroll
        for (int mt = 0; mt < 3; ++mt)
            #pragma unroll
            for (int j = 0; j < 4; ++j) {
                int row = mt*16 + ((lane >> 4) << 2) + j;
                float resid = bf2f(*reinterpret_cast<const unsigned short*>(&s_tokp[row*TSTR + col]));
                s_y[row*YSTR + col] = acc[mt][j] + bv + resid;
            }
    }
    __syncthreads();

    // ---- Stage 7: LayerNorm stats (4 lanes per token) ----
    if (tid < NTOK*4) {   // 192 threads
        int token = tid >> 2, sub = tid & 3;
        const float* row = s_y + token*YSTR + sub*NDH;
        float s = 0.f, s2 = 0.f;
        #pragma unroll
        for (int j = 0; j < NDH; j += 4) {
            float4 v = *reinterpret_cast<const float4*>(row + j);
            s  += v.x + v.y + v.z + v.w;
            s2 += v.x*v.x + v.y*v.y + v.z*v.z + v.w*v.w;
        }
        s  += __shfl_xor(s, 1);  s  += __shfl_xor(s, 2);
        s2 += __shfl_xor(s2, 1); s2 += __shfl_xor(s2, 2);
        float mean = s * (1.f/128.f);
        float var  = s2 * (1.f/128.f) - mean*mean;
        if (sub == 0) {
            s_mu[token]  = mean;
            s_inv[token] = rsqrtf(var + 1e-5f);
        }
    }
    __syncthreads();

    // ---- Stage 8: normalize + coalesced store ----
    #pragma unroll
    for (int i = 0; i < (NTOK*ND)/(NTHR*4); ++i) {   // 3 iters, float4 per thread
        int idx4 = i*NTHR + tid;
        int token = idx4 >> 5;
        int dj = (idx4 & 31) << 2;
        float mean = s_mu[token], inv = s_inv[token];
        float4 v = *reinterpret_cast<const float4*>(s_y + token*YSTR + dj);
        float4 g = *reinterpret_cast<const float4*>(ln_g + dj);
        float4 b = *reinterpret_cast<const float4*>(ln_b + dj);
        float4 r;
        r.x = (v.x-mean)*inv*g.x + b.x;
        r.y = (v.y-mean)*inv*g.y + b.y;
        r.z = (v.z-mean)*inv*g.z + b.z;
        r.w = (v.w-mean)*inv*g.w + b.w;
        *reinterpret_cast<float4*>(out + (frame0*NP + token)*(long)ND + dj) = r;
    }
}

extern "C" void kernel_launch(void* const* d_in, const int* in_sizes, int n_in,
                              void* d_out, int out_size, void* d_ws, size_t ws_size,
                              hipStream_t stream) {
    const float* h_joint = (const float*)d_in[0];
    const float* mask    = (const float*)d_in[1];
    const float* W_proj  = (const float*)d_in[2];
    const float* b_proj  = (const float*)d_in[3];
    const float* W_in    = (const float*)d_in[4];
    const float* b_in    = (const float*)d_in[5];
    const float* W_out   = (const float*)d_in[6];
    const float* b_out   = (const float*)d_in[7];
    const float* ln_g    = (const float*)d_in[8];
    const float* ln_b    = (const float*)d_in[9];
    float* out = (float*)d_out;
    bf16* wgt = (bf16*)d_ws;                     // 81920 bf16 = 160 KB

    hipLaunchKernelGGL(wconv, dim3(81920/256), dim3(256), 0, stream,
                       W_proj, W_in, W_out, wgt);
    hipLaunchKernelGGL(bpa_fused, dim3(NBT/NG), dim3(NTHR), 0, stream,
                       h_joint, mask, wgt, b_proj, b_in, b_out, ln_g, ln_b, out);
}